// Round 2
// 625.459 us; speedup vs baseline: 1.1234x; 1.1234x over previous
//
#include <hip/hip_runtime.h>
#include <hip/hip_bf16.h>

// Qwen3 attention block. Round 5 (resubmit; round-1 bench was an infra
// failure): GQA-shared flash attention.
//   - one block per (qt-tile of 32 rows, kv-head); 4 waves = 4 q-heads of the
//     group share one K/V staging per tile (4x less staging per MFMA).
//   - Q fragments hoisted to registers once per block (no Q LDS, no re-reads).
//   - Ps per-wave-private -> 2 barriers/iter instead of 3.
//   - balanced block mapping: slot0 qt ascending, slot1 qt descending so each
//     CU's two resident blocks sum to ~constant work (kills the triangular tail).
// GEMMs / conversions unchanged from round 4.
// B=1, S=2048, HIDDEN=4096, NQ=32, NKV=8 (GQA R=4), HD=128.

#define S_LEN   2048
#define HIDDEN  4096
#define NQ      32
#define NKV     8
#define HD      128
#define QKV_DIM 6144      // (NQ + 2*NKV) * HD
#define NQHD    4096      // NQ * HD
#define K_OFF   4096
#define V_OFF   5120
#define EPSF    1e-6f

typedef _Float16 half8 __attribute__((ext_vector_type(8)));
typedef _Float16 half4v __attribute__((ext_vector_type(4)));
typedef _Float16 half2v __attribute__((ext_vector_type(2)));
typedef float floatx4 __attribute__((ext_vector_type(4)));

__device__ __forceinline__ void gload_lds16(const void* g, void* l) {
    __builtin_amdgcn_global_load_lds(
        (const __attribute__((address_space(1))) unsigned int*)g,
        (__attribute__((address_space(3))) unsigned int*)l, 16, 0, 0);
}

// ---------------------------------------------------------------------------
// fp32 -> fp16 elementwise convert (8 elems/thread)
// ---------------------------------------------------------------------------
__global__ __launch_bounds__(256) void conv_f32_f16(const float* __restrict__ src,
                                                    _Float16* __restrict__ dst) {
    const size_t i = ((size_t)blockIdx.x * 256 + threadIdx.x) * 8;
    float4 a = *(const float4*)(src + i);
    float4 b = *(const float4*)(src + i + 4);
    half8 h;
    h[0] = (_Float16)a.x; h[1] = (_Float16)a.y; h[2] = (_Float16)a.z; h[3] = (_Float16)a.w;
    h[4] = (_Float16)b.x; h[5] = (_Float16)b.y; h[6] = (_Float16)b.z; h[7] = (_Float16)b.w;
    *(half8*)(dst + i) = h;
}

// ---------------------------------------------------------------------------
// W[K][N] fp32 -> Wt[N][K] fp16 (transpose + convert), 64x64 tiles via LDS.
// ---------------------------------------------------------------------------
__global__ __launch_bounds__(256) void conv_w_transpose(const float* __restrict__ src,
                                                        _Float16* __restrict__ dst,
                                                        int N, int K) {
    __shared__ float T[64][65];
    const int tid = threadIdx.x;
    const int n0 = blockIdx.x * 64, k0 = blockIdx.y * 64;
    const int rr = tid >> 4, cc = (tid & 15) * 4;
    #pragma unroll
    for (int l = 0; l < 4; ++l) {
        const int r = rr + l * 16;
        *(float4*)&T[r][cc] = *(const float4*)(src + (size_t)(k0 + r) * N + n0 + cc);
    }
    __syncthreads();
    #pragma unroll
    for (int l = 0; l < 4; ++l) {
        const int rn = rr + l * 16;
        half4v h;
        h[0] = (_Float16)T[cc + 0][rn];
        h[1] = (_Float16)T[cc + 1][rn];
        h[2] = (_Float16)T[cc + 2][rn];
        h[3] = (_Float16)T[cc + 3][rn];
        *(half4v*)(dst + (size_t)(n0 + rn) * K + k0 + cc) = h;
    }
}

// ---------------------------------------------------------------------------
// m97-style fp16 GEMM: C[M][ldc] = A[M][K] @ Bt[N][K]^T.
// 128x128 tile, BK=32, 4 waves 2x2 (64x64 each, 4x4 MFMA 16x16x32).
// ---------------------------------------------------------------------------
template <typename CT>
__global__ __launch_bounds__(256) void gemm_bt_f16(const _Float16* __restrict__ A,
                                                   const _Float16* __restrict__ Bt,
                                                   CT* __restrict__ C,
                                                   int K, int ldc) {
    __shared__ _Float16 As[128 * 32];
    __shared__ _Float16 Bs[128 * 32];

    const int tid = threadIdx.x;
    const int m0 = blockIdx.y * 128, n0 = blockIdx.x * 128;
    const int wave = tid >> 6, lane = tid & 63;
    const int fl = lane & 15, quad = lane >> 4;
    const int wm = (wave >> 1) * 64, wn = (wave & 1) * 64;

    const int srow = lane >> 2;
    const int skoff = (lane & 3) * 8;

    floatx4 acc[4][4] = {};

    for (int k0 = 0; k0 < K; k0 += 32) {
        __syncthreads();
        #pragma unroll
        for (int i = 0; i < 2; ++i) {
            const int chunk = wave * 2 + i;
            const int row = chunk * 16 + srow;
            gload_lds16(A + (size_t)(m0 + row) * K + k0 + skoff, &As[chunk * 512]);
            gload_lds16(Bt + (size_t)(n0 + row) * K + k0 + skoff, &Bs[chunk * 512]);
        }
        __syncthreads();

        half8 af[4], bf[4];
        #pragma unroll
        for (int t = 0; t < 4; ++t) {
            af[t] = *(const half8*)&As[(wm + t * 16 + fl) * 32 + quad * 8];
            bf[t] = *(const half8*)&Bs[(wn + t * 16 + fl) * 32 + quad * 8];
        }
        #pragma unroll
        for (int i = 0; i < 4; ++i)
            #pragma unroll
            for (int j = 0; j < 4; ++j)
                acc[i][j] = __builtin_amdgcn_mfma_f32_16x16x32_f16(
                    af[i], bf[j], acc[i][j], 0, 0, 0);
    }

    #pragma unroll
    for (int i = 0; i < 4; ++i)
        #pragma unroll
        for (int j = 0; j < 4; ++j)
            #pragma unroll
            for (int r = 0; r < 4; ++r)
                C[(size_t)(m0 + wm + i * 16 + quad * 4 + r) * ldc
                  + n0 + wn + j * 16 + fl] = (CT)acc[i][j][r];
}

// ---------------------------------------------------------------------------
// Fused RMSNorm + RoPE, in-place on fp16 qkv (fp32 math).
// ---------------------------------------------------------------------------
__global__ __launch_bounds__(128) void rmsnorm_rope16(_Float16* __restrict__ qkv,
                                                      const float* __restrict__ qg,
                                                      const float* __restrict__ kg,
                                                      const float* __restrict__ cosb,
                                                      const float* __restrict__ sinb) {
    const int h = blockIdx.x;   // 0..39
    const int s = blockIdx.y;   // 0..2047
    const int d = threadIdx.x;  // 0..127
    const bool isq = (h < NQ);
    const int off = isq ? h * HD : K_OFF + (h - NQ) * HD;
    _Float16* base = qkv + (size_t)s * QKV_DIM + off;

    float x = (float)base[d];
    float ss = x * x;
    #pragma unroll
    for (int o = 32; o; o >>= 1) ss += __shfl_xor(ss, o);

    __shared__ float red[2];
    __shared__ float sh[HD];
    if ((d & 63) == 0) red[d >> 6] = ss;
    __syncthreads();
    float tot = red[0] + red[1];
    float rms = rsqrtf(tot * (1.0f / (float)HD) + EPSF);
    const float* gamma = isq ? qg : kg;
    float xn = x * rms * gamma[d];
    sh[d] = xn;
    __syncthreads();

    float out;
    if (d < 64) {
        float c = cosb[s * 64 + d], sn = sinb[s * 64 + d];
        out = xn * c - sh[d + 64] * sn;
    } else {
        int j = d - 64;
        float c = cosb[s * 64 + j], sn = sinb[s * 64 + j];
        out = xn * c + sh[d - 64] * sn;
    }
    base[d] = (_Float16)out;
}

// ---------------------------------------------------------------------------
// GQA-shared flash attention, fp16 MFMA.
// Block = (qt, kvh): 32 query rows x one kv head. Wave w handles q-head
// kvh*4+w over all 32 rows (2 m-tiles). K/V staged once per tile, shared by
// all 4 waves. Ps per-wave-private -> 2 barriers/iter. Q hoisted to regs.
// Balanced mapping: 512 blocks, slot0 (bd<256) qt ascending, slot1 qt
// descending, so each CU's two resident blocks sum to ~constant work.
// ---------------------------------------------------------------------------
#define FAM 32     // q rows per wave
#define FAN 64     // kv tile rows
#define LQK 136    // Ks row stride (halves): 272 B, 16B-aligned, conflict-ok
#define LVP 68     // Vt/Ps row stride (halves): 136 B, 8B-aligned

__global__ __launch_bounds__(256, 2) void flash_attn_gqa(
        const _Float16* __restrict__ qkv, _Float16* __restrict__ attn) {
    __shared__ __align__(16) _Float16 Ks[FAN][LQK];     // 17408 B
    __shared__ __align__(16) _Float16 Vt[HD][LVP];      // 17408 B, V transposed
    __shared__ __align__(16) _Float16 Ps[4][FAM][LVP];  // 17408 B, per-wave

    const int tid = threadIdx.x;
    const int wave = tid >> 6, lane = tid & 63;
    const int fl = lane & 15, quad = lane >> 4;

    // balanced (qt, kvh) mapping over 512 blocks
    const int bd = blockIdx.x;
    const int c = bd & 255, sflip = bd >> 8;
    const int qt = sflip ? 63 - (c & 63) : (c & 63);
    const int kvh = (sflip << 2) + (c >> 6);
    const int h = kvh * 4 + wave;
    const int m0 = qt * FAM;
    const float scale = 0.08838834764831845f;  // HD^-0.5

    // ---- hoist Q fragments: qf[mt][ks] covers rows m0+mt*16+fl ----
    half8 qf[2][4];
    #pragma unroll
    for (int mt = 0; mt < 2; ++mt)
        #pragma unroll
        for (int ks = 0; ks < 4; ++ks)
            qf[mt][ks] = *(const half8*)(qkv
                + (size_t)(m0 + mt * 16 + fl) * QKV_DIM + h * HD + ks * 32 + quad * 8);

    float m_prev[2][4], l_prev[2][4];
    #pragma unroll
    for (int mt = 0; mt < 2; ++mt)
        #pragma unroll
        for (int r = 0; r < 4; ++r) { m_prev[mt][r] = -1e30f; l_prev[mt][r] = 0.f; }
    floatx4 oacc[2][8] = {};

    const int tmax = (m0 + FAM - 1) / FAN;   // only this tile crosses the diagonal
    for (int t = 0; t <= tmax; ++t) {
        const int n0 = t * FAN;
        __syncthreads();   // (A) all waves done reading prev Ks/Vt

        // K tile [j][d] -> Ks (padded)
        #pragma unroll
        for (int l = 0; l < 4; ++l) {
            const int f = tid + l * 256;
            const int r = f >> 4, c8 = (f & 15) * 8;
            *(half8*)&Ks[r][c8] = *(const half8*)(qkv
                + (size_t)(n0 + r) * QKV_DIM + K_OFF + kvh * HD + c8);
        }
        // V tile transposed Vt[d][j]
        {
            const int p = tid & 31, g0 = tid >> 5;
            #pragma unroll
            for (int gi = 0; gi < 2; ++gi) {
                const int g = g0 + gi * 8;           // d = 8g..8g+7
                const _Float16* v0p = qkv + (size_t)(n0 + 2 * p) * QKV_DIM
                                      + V_OFF + kvh * HD + 8 * g;
                half8 va = *(const half8*)v0p;
                half8 vb = *(const half8*)(v0p + QKV_DIM);
                #pragma unroll
                for (int i = 0; i < 8; ++i) {
                    half2v hh; hh[0] = va[i]; hh[1] = vb[i];
                    *(half2v*)&Vt[8 * g + i][2 * p] = hh;
                }
            }
        }
        __syncthreads();   // (B) tiles staged

        // ---- QK^T: 2 m-tiles x 4 n-tiles ----
        floatx4 sacc[2][4] = {};
        __builtin_amdgcn_s_setprio(1);
        #pragma unroll
        for (int ks = 0; ks < 4; ++ks)
            #pragma unroll
            for (int nt = 0; nt < 4; ++nt) {
                half8 bf = *(const half8*)&Ks[nt * 16 + fl][ks * 32 + quad * 8];
                sacc[0][nt] = __builtin_amdgcn_mfma_f32_16x16x32_f16(
                    qf[0][ks], bf, sacc[0][nt], 0, 0, 0);
                sacc[1][nt] = __builtin_amdgcn_mfma_f32_16x16x32_f16(
                    qf[1][ks], bf, sacc[1][nt], 0, 0, 0);
            }
        __builtin_amdgcn_s_setprio(0);

        // ---- online softmax (rows mt*16 + quad*4 + r) ----
        const bool diag = (t == tmax);
        float mx[2][4];
        #pragma unroll
        for (int mt = 0; mt < 2; ++mt)
            #pragma unroll
            for (int r = 0; r < 4; ++r) mx[mt][r] = -1e30f;
        #pragma unroll
        for (int mt = 0; mt < 2; ++mt)
            #pragma unroll
            for (int nt = 0; nt < 4; ++nt)
                #pragma unroll
                for (int r = 0; r < 4; ++r) {
                    float sv = sacc[mt][nt][r] * scale;
                    if (diag && (n0 + nt * 16 + fl > m0 + mt * 16 + quad * 4 + r))
                        sv = -1e30f;
                    sacc[mt][nt][r] = sv;
                    mx[mt][r] = fmaxf(mx[mt][r], sv);
                }
        #pragma unroll
        for (int mt = 0; mt < 2; ++mt)
            #pragma unroll
            for (int r = 0; r < 4; ++r)
                #pragma unroll
                for (int o = 8; o; o >>= 1)
                    mx[mt][r] = fmaxf(mx[mt][r], __shfl_xor(mx[mt][r], o));

        float alpha[2][4], rs[2][4];
        #pragma unroll
        for (int mt = 0; mt < 2; ++mt)
            #pragma unroll
            for (int r = 0; r < 4; ++r) {
                float nm = fmaxf(m_prev[mt][r], mx[mt][r]);
                alpha[mt][r] = __expf(m_prev[mt][r] - nm);
                m_prev[mt][r] = nm;
                rs[mt][r] = 0.f;
            }
        #pragma unroll
        for (int mt = 0; mt < 2; ++mt)
            #pragma unroll
            for (int nt = 0; nt < 4; ++nt)
                #pragma unroll
                for (int r = 0; r < 4; ++r) {
                    float p = __expf(sacc[mt][nt][r] - m_prev[mt][r]);
                    rs[mt][r] += p;
                    Ps[wave][mt * 16 + quad * 4 + r][nt * 16 + fl] = (_Float16)p;
                }
        #pragma unroll
        for (int mt = 0; mt < 2; ++mt)
            #pragma unroll
            for (int r = 0; r < 4; ++r) {
                #pragma unroll
                for (int o = 8; o; o >>= 1) rs[mt][r] += __shfl_xor(rs[mt][r], o);
                l_prev[mt][r] = l_prev[mt][r] * alpha[mt][r] + rs[mt][r];
            }
        #pragma unroll
        for (int mt = 0; mt < 2; ++mt)
            #pragma unroll
            for (int dt = 0; dt < 8; ++dt)
                #pragma unroll
                for (int r = 0; r < 4; ++r) oacc[mt][dt][r] *= alpha[mt][r];

        // ---- PV (same-wave Ps: no barrier; lgkmcnt orders write->read) ----
        __builtin_amdgcn_s_setprio(1);
        #pragma unroll
        for (int ks2 = 0; ks2 < 2; ++ks2) {
            half8 pa[2];
            #pragma unroll
            for (int mt = 0; mt < 2; ++mt) {
                half4v plo = *(const half4v*)&Ps[wave][mt * 16 + fl][ks2 * 32 + quad * 8];
                half4v phi = *(const half4v*)&Ps[wave][mt * 16 + fl][ks2 * 32 + quad * 8 + 4];
                pa[mt] = __builtin_shufflevector(plo, phi, 0, 1, 2, 3, 4, 5, 6, 7);
            }
            #pragma unroll
            for (int dt = 0; dt < 8; ++dt) {
                half4v vlo = *(const half4v*)&Vt[dt * 16 + fl][ks2 * 32 + quad * 8];
                half4v vhi = *(const half4v*)&Vt[dt * 16 + fl][ks2 * 32 + quad * 8 + 4];
                half8 vb = __builtin_shufflevector(vlo, vhi, 0, 1, 2, 3, 4, 5, 6, 7);
                oacc[0][dt] = __builtin_amdgcn_mfma_f32_16x16x32_f16(
                    pa[0], vb, oacc[0][dt], 0, 0, 0);
                oacc[1][dt] = __builtin_amdgcn_mfma_f32_16x16x32_f16(
                    pa[1], vb, oacc[1][dt], 0, 0, 0);
            }
        }
        __builtin_amdgcn_s_setprio(0);
    }

    #pragma unroll
    for (int mt = 0; mt < 2; ++mt) {
        float linv[4];
        #pragma unroll
        for (int r = 0; r < 4; ++r) linv[r] = 1.0f / l_prev[mt][r];
        #pragma unroll
        for (int dt = 0; dt < 8; ++dt)
            #pragma unroll
            for (int r = 0; r < 4; ++r)
                attn[(size_t)(m0 + mt * 16 + quad * 4 + r) * NQHD
                     + h * HD + dt * 16 + fl] = (_Float16)(oacc[mt][dt][r] * linv[r]);
    }
}

// ---------------------------------------------------------------------------
extern "C" void kernel_launch(void* const* d_in, const int* in_sizes, int n_in,
                              void* d_out, int out_size, void* d_ws, size_t ws_size,
                              hipStream_t stream) {
    // inputs: positions, hidden_states, Wqkv, Wo, q_gamma, k_gamma, cos, sin
    const float* hidden = (const float*)d_in[1];
    const float* Wqkv   = (const float*)d_in[2];
    const float* Wo     = (const float*)d_in[3];
    const float* qg     = (const float*)d_in[4];
    const float* kg     = (const float*)d_in[5];
    const float* cosb   = (const float*)d_in[6];
    const float* sinb   = (const float*)d_in[7];
    float* out = (float*)d_out;

    // ws layout (67.1 MB total):
    //   buf0: h16 [2048][4096]     -> later attn16 [2048][4096] (same size)
    //   buf1: wT  [6144][4096]     -> later woT [4096][4096] (smaller)
    // qkv16 [2048][6144] fp16 lives in d_out; dead before gemm2 overwrites it.
    _Float16* buf0  = (_Float16*)d_ws;
    _Float16* wT    = buf0 + (size_t)S_LEN * HIDDEN;
    _Float16* qkv16 = (_Float16*)d_out;
    _Float16* attn16 = buf0;

    // 1) convert hidden -> fp16
    conv_f32_f16<<<(S_LEN * HIDDEN) / 2048, 256, 0, stream>>>(hidden, buf0);
    // 2) Wqkv [K=4096][N=6144] -> wT [6144][4096] fp16
    conv_w_transpose<<<dim3(QKV_DIM / 64, HIDDEN / 64), 256, 0, stream>>>(
        Wqkv, wT, QKV_DIM, HIDDEN);
    // 3) qkv16 = h16 @ wT^T
    gemm_bt_f16<_Float16><<<dim3(QKV_DIM / 128, S_LEN / 128), 256, 0, stream>>>(
        buf0, wT, qkv16, HIDDEN, QKV_DIM);
    // 4) RMSNorm + RoPE in place (fp16)
    rmsnorm_rope16<<<dim3(NQ + NKV, S_LEN), 128, 0, stream>>>(qkv16, qg, kg, cosb, sinb);
    // 5) GQA-shared flash attention -> attn16 (buf0; h16 dead)
    flash_attn_gqa<<<dim3((S_LEN / FAM) * NKV), 256, 0, stream>>>(qkv16, attn16);
    // 6) Wo [4096][4096] -> woT fp16 (reuses wT slot; Wqkv16 dead)
    conv_w_transpose<<<dim3(HIDDEN / 64, NQHD / 64), 256, 0, stream>>>(
        Wo, wT, HIDDEN, NQHD);
    // 7) out = attn16 @ woT^T (fp32 store; overwrites qkv16 scratch)
    gemm_bt_f16<float><<<dim3(HIDDEN / 128, S_LEN / 128), 256, 0, stream>>>(
        attn16, wT, out, NQHD, HIDDEN);
}

// Round 3
// 605.027 us; speedup vs baseline: 1.1613x; 1.0338x over previous
//
#include <hip/hip_runtime.h>
#include <hip/hip_bf16.h>

// Qwen3 attention block. Round 6: deep-pipelined 256-wide GEMMs.
//   - gemm_bt_256<CT,BM>: BMx256 tile, BK=64, 8 waves (2Mx4N), 512 thr,
//     double-buffered K-tiles, counted vmcnt (8 / 6, never 0 in loop),
//     raw asm barriers (no compiler vmcnt(0) drain), T2 chunk^row&7 LDS
//     swizzle via pre-swizzled gload_lds SOURCE (rule #21), 4 phases of
//     16 MFMA with setprio. Numerically identical k-order to round 5.
//   - QKV: 256x256 (192 blocks); Wo: 128x256 (256 blocks, full fill).
// Flash attention / conversions / rmsnorm unchanged from round 5.
// B=1, S=2048, HIDDEN=4096, NQ=32, NKV=8 (GQA R=4), HD=128.

#define S_LEN   2048
#define HIDDEN  4096
#define NQ      32
#define NKV     8
#define HD      128
#define QKV_DIM 6144      // (NQ + 2*NKV) * HD
#define NQHD    4096      // NQ * HD
#define K_OFF   4096
#define V_OFF   5120
#define EPSF    1e-6f

typedef _Float16 half8 __attribute__((ext_vector_type(8)));
typedef _Float16 half4v __attribute__((ext_vector_type(4)));
typedef _Float16 half2v __attribute__((ext_vector_type(2)));
typedef float floatx4 __attribute__((ext_vector_type(4)));

__device__ __forceinline__ void gload_lds16(const void* g, void* l) {
    __builtin_amdgcn_global_load_lds(
        (const __attribute__((address_space(1))) unsigned int*)g,
        (__attribute__((address_space(3))) unsigned int*)l, 16, 0, 0);
}

// ---------------------------------------------------------------------------
// fp32 -> fp16 elementwise convert (8 elems/thread)
// ---------------------------------------------------------------------------
__global__ __launch_bounds__(256) void conv_f32_f16(const float* __restrict__ src,
                                                    _Float16* __restrict__ dst) {
    const size_t i = ((size_t)blockIdx.x * 256 + threadIdx.x) * 8;
    float4 a = *(const float4*)(src + i);
    float4 b = *(const float4*)(src + i + 4);
    half8 h;
    h[0] = (_Float16)a.x; h[1] = (_Float16)a.y; h[2] = (_Float16)a.z; h[3] = (_Float16)a.w;
    h[4] = (_Float16)b.x; h[5] = (_Float16)b.y; h[6] = (_Float16)b.z; h[7] = (_Float16)b.w;
    *(half8*)(dst + i) = h;
}

// ---------------------------------------------------------------------------
// W[K][N] fp32 -> Wt[N][K] fp16 (transpose + convert), 64x64 tiles via LDS.
// ---------------------------------------------------------------------------
__global__ __launch_bounds__(256) void conv_w_transpose(const float* __restrict__ src,
                                                        _Float16* __restrict__ dst,
                                                        int N, int K) {
    __shared__ float T[64][65];
    const int tid = threadIdx.x;
    const int n0 = blockIdx.x * 64, k0 = blockIdx.y * 64;
    const int rr = tid >> 4, cc = (tid & 15) * 4;
    #pragma unroll
    for (int l = 0; l < 4; ++l) {
        const int r = rr + l * 16;
        *(float4*)&T[r][cc] = *(const float4*)(src + (size_t)(k0 + r) * N + n0 + cc);
    }
    __syncthreads();
    #pragma unroll
    for (int l = 0; l < 4; ++l) {
        const int rn = rr + l * 16;
        half4v h;
        h[0] = (_Float16)T[cc + 0][rn];
        h[1] = (_Float16)T[cc + 1][rn];
        h[2] = (_Float16)T[cc + 2][rn];
        h[3] = (_Float16)T[cc + 3][rn];
        *(half4v*)(dst + (size_t)(n0 + rn) * K + k0 + cc) = h;
    }
}

// ---------------------------------------------------------------------------
// Deep-pipelined GEMM: C[M][ldc] = A[M][K] @ Bt[N][K]^T, fp16 in, CT out.
// Tile BM x 256, BK=64, 512 threads = 8 waves (2M x 4N), per-wave BM/2 x 64.
// Double-buffered K-tiles; counted vmcnt; swizzled LDS (chunk ^= row&7 at
// 16B granularity) with pre-swizzled global source for gload_lds.
// ---------------------------------------------------------------------------
template <typename CT, int BM>
__global__ __launch_bounds__(512, 2) void gemm_bt_256(const _Float16* __restrict__ A,
                                                      const _Float16* __restrict__ Bt,
                                                      CT* __restrict__ C,
                                                      int K, int ldc) {
    constexpr int QM = BM / 128;      // 2 (BM=256) or 1 (BM=128) phase-groups in M
    constexpr int AL = BM / 64;       // A gload_lds per thread per tile (4 or 2)
    constexpr int MI = QM * 4;        // m-tiles per wave (8 or 4)

    __shared__ _Float16 ldsA[2][BM * 64];
    __shared__ _Float16 ldsB[2][256 * 64];

    const int tid = threadIdx.x;
    const int wave = tid >> 6, lane = tid & 63;
    const int fl = lane & 15, quad = lane >> 4;

    // bijective XCD swizzle on flattened block id (nwg % 8 == 0 for our grids)
    const int nwg = gridDim.x * gridDim.y;
    int bid = blockIdx.y * gridDim.x + blockIdx.x;
    bid = (bid & 7) * (nwg >> 3) + (bid >> 3);
    const int m0 = (bid / gridDim.x) * BM;
    const int n0 = (bid % gridDim.x) * 256;

    const int wm = (wave >> 2) * (BM / 2);   // wave row base (0 / BM/2)
    const int wn = (wave & 3) * 64;          // wave col base

    // staging lane geometry: 64 lanes x 16B = 8 rows x 128B per instruction.
    // LDS dest is linear; SOURCE chunk is pre-swizzled: chunk' = (l&7)^(row&7).
    const int srow8 = lane >> 3;                       // row within 8-row group
    const int schunk = ((lane & 7) ^ srow8) * 8;       // halves offset in K-slice

    auto stage = [&](int p, int kt) {
        const int kb = kt * 64;
        #pragma unroll
        for (int i = 0; i < AL; ++i) {
            const int r0 = i * 64 + wave * 8;
            gload_lds16(A + (size_t)(m0 + r0 + srow8) * K + kb + schunk,
                        &ldsA[p][r0 * 64]);
        }
        #pragma unroll
        for (int i = 0; i < 4; ++i) {
            const int r0 = i * 64 + wave * 8;
            gload_lds16(Bt + (size_t)(n0 + r0 + srow8) * K + kb + schunk,
                        &ldsB[p][r0 * 64]);
        }
    };

    floatx4 acc[MI][4] = {};

    stage(0, 0);
    stage(1, 1);

    // swizzled ds_read byte offsets for k-steps 0/1 (chunk ^= fl&7; row base
    // offsets are all multiples of 8, so row&7 == fl&7)
    const int cs0 = ((quad ^ (fl & 7)) << 4);
    const int cs1 = (((4 + quad) ^ (fl & 7)) << 4);

    const int NT = K >> 6;
    for (int t = 0; t < NT; ++t) {
        // wait current tile landed (oldest VW loads), then barrier. Combined
        // in one asm with memory clobber so no LDS read hoists above it.
        if (t == NT - 1) {
            asm volatile("s_waitcnt vmcnt(0)\n\ts_barrier" ::: "memory");
        } else {
            if constexpr (AL + 4 == 8)
                asm volatile("s_waitcnt vmcnt(8)\n\ts_barrier" ::: "memory");
            else
                asm volatile("s_waitcnt vmcnt(6)\n\ts_barrier" ::: "memory");
        }

        const char* Asb = (const char*)ldsA[t & 1];
        const char* Bsb = (const char*)ldsB[t & 1];

        #pragma unroll
        for (int qm = 0; qm < QM; ++qm) {
            half8 af[4][2];
            #pragma unroll
            for (int mt = 0; mt < 4; ++mt) {
                const char* rb = Asb + (wm + qm * 64 + mt * 16 + fl) * 128;
                af[mt][0] = *(const half8*)(rb + cs0);
                af[mt][1] = *(const half8*)(rb + cs1);
            }
            #pragma unroll
            for (int qn = 0; qn < 2; ++qn) {
                half8 bf[2][2];
                #pragma unroll
                for (int nt = 0; nt < 2; ++nt) {
                    const char* rb = Bsb + (wn + qn * 32 + nt * 16 + fl) * 128;
                    bf[nt][0] = *(const half8*)(rb + cs0);
                    bf[nt][1] = *(const half8*)(rb + cs1);
                }
                __builtin_amdgcn_s_setprio(1);
                #pragma unroll
                for (int ks = 0; ks < 2; ++ks)
                    #pragma unroll
                    for (int mt = 0; mt < 4; ++mt)
                        #pragma unroll
                        for (int nt = 0; nt < 2; ++nt)
                            acc[qm * 4 + mt][qn * 2 + nt] =
                                __builtin_amdgcn_mfma_f32_16x16x32_f16(
                                    af[mt][ks], bf[nt][ks],
                                    acc[qm * 4 + mt][qn * 2 + nt], 0, 0, 0);
                __builtin_amdgcn_s_setprio(0);
            }
        }

        // all waves done reading buf[t&1]; then refill it with tile t+2.
        asm volatile("s_barrier" ::: "memory");
        if (t + 2 < NT) stage(t & 1, t + 2);
    }

    #pragma unroll
    for (int mi = 0; mi < MI; ++mi)
        #pragma unroll
        for (int ni = 0; ni < 4; ++ni)
            #pragma unroll
            for (int r = 0; r < 4; ++r)
                C[(size_t)(m0 + wm + mi * 16 + quad * 4 + r) * ldc
                  + n0 + wn + ni * 16 + fl] = (CT)acc[mi][ni][r];
}

// ---------------------------------------------------------------------------
// Fused RMSNorm + RoPE, in-place on fp16 qkv (fp32 math).
// ---------------------------------------------------------------------------
__global__ __launch_bounds__(128) void rmsnorm_rope16(_Float16* __restrict__ qkv,
                                                      const float* __restrict__ qg,
                                                      const float* __restrict__ kg,
                                                      const float* __restrict__ cosb,
                                                      const float* __restrict__ sinb) {
    const int h = blockIdx.x;   // 0..39
    const int s = blockIdx.y;   // 0..2047
    const int d = threadIdx.x;  // 0..127
    const bool isq = (h < NQ);
    const int off = isq ? h * HD : K_OFF + (h - NQ) * HD;
    _Float16* base = qkv + (size_t)s * QKV_DIM + off;

    float x = (float)base[d];
    float ss = x * x;
    #pragma unroll
    for (int o = 32; o; o >>= 1) ss += __shfl_xor(ss, o);

    __shared__ float red[2];
    __shared__ float sh[HD];
    if ((d & 63) == 0) red[d >> 6] = ss;
    __syncthreads();
    float tot = red[0] + red[1];
    float rms = rsqrtf(tot * (1.0f / (float)HD) + EPSF);
    const float* gamma = isq ? qg : kg;
    float xn = x * rms * gamma[d];
    sh[d] = xn;
    __syncthreads();

    float out;
    if (d < 64) {
        float c = cosb[s * 64 + d], sn = sinb[s * 64 + d];
        out = xn * c - sh[d + 64] * sn;
    } else {
        int j = d - 64;
        float c = cosb[s * 64 + j], sn = sinb[s * 64 + j];
        out = xn * c + sh[d - 64] * sn;
    }
    base[d] = (_Float16)out;
}

// ---------------------------------------------------------------------------
// GQA-shared flash attention, fp16 MFMA (verified round 5).
// ---------------------------------------------------------------------------
#define FAM 32     // q rows per wave
#define FAN 64     // kv tile rows
#define LQK 136    // Ks row stride (halves)
#define LVP 68     // Vt/Ps row stride (halves)

__global__ __launch_bounds__(256, 2) void flash_attn_gqa(
        const _Float16* __restrict__ qkv, _Float16* __restrict__ attn) {
    __shared__ __align__(16) _Float16 Ks[FAN][LQK];
    __shared__ __align__(16) _Float16 Vt[HD][LVP];
    __shared__ __align__(16) _Float16 Ps[4][FAM][LVP];

    const int tid = threadIdx.x;
    const int wave = tid >> 6, lane = tid & 63;
    const int fl = lane & 15, quad = lane >> 4;

    const int bd = blockIdx.x;
    const int c = bd & 255, sflip = bd >> 8;
    const int qt = sflip ? 63 - (c & 63) : (c & 63);
    const int kvh = (sflip << 2) + (c >> 6);
    const int h = kvh * 4 + wave;
    const int m0 = qt * FAM;
    const float scale = 0.08838834764831845f;  // HD^-0.5

    half8 qf[2][4];
    #pragma unroll
    for (int mt = 0; mt < 2; ++mt)
        #pragma unroll
        for (int ks = 0; ks < 4; ++ks)
            qf[mt][ks] = *(const half8*)(qkv
                + (size_t)(m0 + mt * 16 + fl) * QKV_DIM + h * HD + ks * 32 + quad * 8);

    float m_prev[2][4], l_prev[2][4];
    #pragma unroll
    for (int mt = 0; mt < 2; ++mt)
        #pragma unroll
        for (int r = 0; r < 4; ++r) { m_prev[mt][r] = -1e30f; l_prev[mt][r] = 0.f; }
    floatx4 oacc[2][8] = {};

    const int tmax = (m0 + FAM - 1) / FAN;
    for (int t = 0; t <= tmax; ++t) {
        const int n0 = t * FAN;
        __syncthreads();   // (A) all waves done reading prev Ks/Vt

        #pragma unroll
        for (int l = 0; l < 4; ++l) {
            const int f = tid + l * 256;
            const int r = f >> 4, c8 = (f & 15) * 8;
            *(half8*)&Ks[r][c8] = *(const half8*)(qkv
                + (size_t)(n0 + r) * QKV_DIM + K_OFF + kvh * HD + c8);
        }
        {
            const int p = tid & 31, g0 = tid >> 5;
            #pragma unroll
            for (int gi = 0; gi < 2; ++gi) {
                const int g = g0 + gi * 8;
                const _Float16* v0p = qkv + (size_t)(n0 + 2 * p) * QKV_DIM
                                      + V_OFF + kvh * HD + 8 * g;
                half8 va = *(const half8*)v0p;
                half8 vb = *(const half8*)(v0p + QKV_DIM);
                #pragma unroll
                for (int i = 0; i < 8; ++i) {
                    half2v hh; hh[0] = va[i]; hh[1] = vb[i];
                    *(half2v*)&Vt[8 * g + i][2 * p] = hh;
                }
            }
        }
        __syncthreads();   // (B) tiles staged

        floatx4 sacc[2][4] = {};
        __builtin_amdgcn_s_setprio(1);
        #pragma unroll
        for (int ks = 0; ks < 4; ++ks)
            #pragma unroll
            for (int nt = 0; nt < 4; ++nt) {
                half8 bf = *(const half8*)&Ks[nt * 16 + fl][ks * 32 + quad * 8];
                sacc[0][nt] = __builtin_amdgcn_mfma_f32_16x16x32_f16(
                    qf[0][ks], bf, sacc[0][nt], 0, 0, 0);
                sacc[1][nt] = __builtin_amdgcn_mfma_f32_16x16x32_f16(
                    qf[1][ks], bf, sacc[1][nt], 0, 0, 0);
            }
        __builtin_amdgcn_s_setprio(0);

        const bool diag = (t == tmax);
        float mx[2][4];
        #pragma unroll
        for (int mt = 0; mt < 2; ++mt)
            #pragma unroll
            for (int r = 0; r < 4; ++r) mx[mt][r] = -1e30f;
        #pragma unroll
        for (int mt = 0; mt < 2; ++mt)
            #pragma unroll
            for (int nt = 0; nt < 4; ++nt)
                #pragma unroll
                for (int r = 0; r < 4; ++r) {
                    float sv = sacc[mt][nt][r] * scale;
                    if (diag && (n0 + nt * 16 + fl > m0 + mt * 16 + quad * 4 + r))
                        sv = -1e30f;
                    sacc[mt][nt][r] = sv;
                    mx[mt][r] = fmaxf(mx[mt][r], sv);
                }
        #pragma unroll
        for (int mt = 0; mt < 2; ++mt)
            #pragma unroll
            for (int r = 0; r < 4; ++r)
                #pragma unroll
                for (int o = 8; o; o >>= 1)
                    mx[mt][r] = fmaxf(mx[mt][r], __shfl_xor(mx[mt][r], o));

        float alpha[2][4], rs[2][4];
        #pragma unroll
        for (int mt = 0; mt < 2; ++mt)
            #pragma unroll
            for (int r = 0; r < 4; ++r) {
                float nm = fmaxf(m_prev[mt][r], mx[mt][r]);
                alpha[mt][r] = __expf(m_prev[mt][r] - nm);
                m_prev[mt][r] = nm;
                rs[mt][r] = 0.f;
            }
        #pragma unroll
        for (int mt = 0; mt < 2; ++mt)
            #pragma unroll
            for (int nt = 0; nt < 4; ++nt)
                #pragma unroll
                for (int r = 0; r < 4; ++r) {
                    float p = __expf(sacc[mt][nt][r] - m_prev[mt][r]);
                    rs[mt][r] += p;
                    Ps[wave][mt * 16 + quad * 4 + r][nt * 16 + fl] = (_Float16)p;
                }
        #pragma unroll
        for (int mt = 0; mt < 2; ++mt)
            #pragma unroll
            for (int r = 0; r < 4; ++r) {
                #pragma unroll
                for (int o = 8; o; o >>= 1) rs[mt][r] += __shfl_xor(rs[mt][r], o);
                l_prev[mt][r] = l_prev[mt][r] * alpha[mt][r] + rs[mt][r];
            }
        #pragma unroll
        for (int mt = 0; mt < 2; ++mt)
            #pragma unroll
            for (int dt = 0; dt < 8; ++dt)
                #pragma unroll
                for (int r = 0; r < 4; ++r) oacc[mt][dt][r] *= alpha[mt][r];

        __builtin_amdgcn_s_setprio(1);
        #pragma unroll
        for (int ks2 = 0; ks2 < 2; ++ks2) {
            half8 pa[2];
            #pragma unroll
            for (int mt = 0; mt < 2; ++mt) {
                half4v plo = *(const half4v*)&Ps[wave][mt * 16 + fl][ks2 * 32 + quad * 8];
                half4v phi = *(const half4v*)&Ps[wave][mt * 16 + fl][ks2 * 32 + quad * 8 + 4];
                pa[mt] = __builtin_shufflevector(plo, phi, 0, 1, 2, 3, 4, 5, 6, 7);
            }
            #pragma unroll
            for (int dt = 0; dt < 8; ++dt) {
                half4v vlo = *(const half4v*)&Vt[dt * 16 + fl][ks2 * 32 + quad * 8];
                half4v vhi = *(const half4v*)&Vt[dt * 16 + fl][ks2 * 32 + quad * 8 + 4];
                half8 vb = __builtin_shufflevector(vlo, vhi, 0, 1, 2, 3, 4, 5, 6, 7);
                oacc[0][dt] = __builtin_amdgcn_mfma_f32_16x16x32_f16(
                    pa[0], vb, oacc[0][dt], 0, 0, 0);
                oacc[1][dt] = __builtin_amdgcn_mfma_f32_16x16x32_f16(
                    pa[1], vb, oacc[1][dt], 0, 0, 0);
            }
        }
        __builtin_amdgcn_s_setprio(0);
    }

    #pragma unroll
    for (int mt = 0; mt < 2; ++mt) {
        float linv[4];
        #pragma unroll
        for (int r = 0; r < 4; ++r) linv[r] = 1.0f / l_prev[mt][r];
        #pragma unroll
        for (int dt = 0; dt < 8; ++dt)
            #pragma unroll
            for (int r = 0; r < 4; ++r)
                attn[(size_t)(m0 + mt * 16 + quad * 4 + r) * NQHD
                     + h * HD + dt * 16 + fl] = (_Float16)(oacc[mt][dt][r] * linv[r]);
    }
}

// ---------------------------------------------------------------------------
extern "C" void kernel_launch(void* const* d_in, const int* in_sizes, int n_in,
                              void* d_out, int out_size, void* d_ws, size_t ws_size,
                              hipStream_t stream) {
    // inputs: positions, hidden_states, Wqkv, Wo, q_gamma, k_gamma, cos, sin
    const float* hidden = (const float*)d_in[1];
    const float* Wqkv   = (const float*)d_in[2];
    const float* Wo     = (const float*)d_in[3];
    const float* qg     = (const float*)d_in[4];
    const float* kg     = (const float*)d_in[5];
    const float* cosb   = (const float*)d_in[6];
    const float* sinb   = (const float*)d_in[7];
    float* out = (float*)d_out;

    // ws layout (67.1 MB total):
    //   buf0: h16 [2048][4096]     -> later attn16 [2048][4096] (same size)
    //   buf1: wT  [6144][4096]     -> later woT [4096][4096] (smaller)
    // qkv16 [2048][6144] fp16 lives in d_out; dead before gemm2 overwrites it.
    _Float16* buf0  = (_Float16*)d_ws;
    _Float16* wT    = buf0 + (size_t)S_LEN * HIDDEN;
    _Float16* qkv16 = (_Float16*)d_out;
    _Float16* attn16 = buf0;

    // 1) convert hidden -> fp16
    conv_f32_f16<<<(S_LEN * HIDDEN) / 2048, 256, 0, stream>>>(hidden, buf0);
    // 2) Wqkv [K=4096][N=6144] -> wT [6144][4096] fp16
    conv_w_transpose<<<dim3(QKV_DIM / 64, HIDDEN / 64), 256, 0, stream>>>(
        Wqkv, wT, QKV_DIM, HIDDEN);
    // 3) qkv16 = h16 @ wT^T  (256x256 tiles, 24x8 = 192 blocks)
    gemm_bt_256<_Float16, 256><<<dim3(QKV_DIM / 256, S_LEN / 256), 512, 0, stream>>>(
        buf0, wT, qkv16, HIDDEN, QKV_DIM);
    // 4) RMSNorm + RoPE in place (fp16)
    rmsnorm_rope16<<<dim3(NQ + NKV, S_LEN), 128, 0, stream>>>(qkv16, qg, kg, cosb, sinb);
    // 5) GQA-shared flash attention -> attn16 (buf0; h16 dead)
    flash_attn_gqa<<<dim3((S_LEN / FAM) * NKV), 256, 0, stream>>>(qkv16, attn16);
    // 6) Wo [4096][4096] -> woT fp16 (reuses wT slot; Wqkv16 dead)
    conv_w_transpose<<<dim3(HIDDEN / 64, NQHD / 64), 256, 0, stream>>>(
        Wo, wT, HIDDEN, NQHD);
    // 7) out = attn16 @ woT^T  (128x256 tiles, 16x16 = 256 blocks, full fill)
    gemm_bt_256<float, 128><<<dim3(HIDDEN / 256, S_LEN / 128), 512, 0, stream>>>(
        attn16, wT, out, NQHD, HIDDEN);
}